// Round 9
// baseline (404.253 us; speedup 1.0000x reference)
//
#include <hip/hip_runtime.h>

// GRU H=31, B=2048, T=512, FC->2, three-phase:
//  1) pack_wih: W_ih -> packed f16 pairs in ws, PRE-SCALED (r/z rows x log2e,
//     n rows x 2log2e) so the recurrence uses v_exp (=2^x) natively.
//  2) xg_gemm:  xg[b][row][t] = (b_ih[row] + x . W_ih[row]) * scale  (f16, ws)
//  3) gru_mfma: 1 batch per wave64 (2048 waves = 2/SIMD), W_hh.h via MFMA:
//     6x v_mfma_f32_16x16x32_f16 per step compute all 96 rows (93 GRU rows,
//     row 93 pad, rows 94/95 = FC head), biases in the C-in operand.
//     B-frag = h broadcast: B[k][col]=h[k] -> lane reads h[grp*8..+7] with
//     ONE ds_read_b128 (same-address broadcast per 16-lane group).
//     A-frag: row=lane&15 (global 16c+row), k=grp*8+i, f16, pre-scaled.
//     C/D: col=lane&15, row=grp*4+j  [m89-verified mapping].
//     Redistribute: col==0 lanes write D_c (f32x4) -> preF[16c+4g]; gate
//     lanes (0..30) read {pr,pz,pn} + xg streams, exp2 gates, write h f16.
//     No barriers (in-wave DS ordering); compiler fences per r4 lesson.

constexpr int BB = 2048, TT = 512, HH = 31;
constexpr int RR = 96;                                  // padded xg rows
constexpr size_t XG_BYTES = (size_t)BB * RR * TT * 2;   // 201326592
constexpr int WPAIRS = 93 * 16;
constexpr size_t WS_NEEDED = XG_BYTES + (size_t)WPAIRS * 4;
constexpr float LOG2E = 1.4426950408889634f;

#define MEMFENCE asm volatile("" ::: "memory")

typedef _Float16 hf2 __attribute__((ext_vector_type(2)));
typedef _Float16 hf8 __attribute__((ext_vector_type(8)));
typedef float f32x4 __attribute__((ext_vector_type(4)));

__device__ __forceinline__ float dot2(int a, hf2 w, float acc) {
#if __has_builtin(__builtin_amdgcn_fdot2)
    return __builtin_amdgcn_fdot2(__builtin_bit_cast(hf2, a), w, acc, false);
#else
    hf2 x = __builtin_bit_cast(hf2, a);
    return acc + (float)x.x * (float)w.x + (float)x.y * (float)w.y;
#endif
}

__device__ __forceinline__ float fast_exp2(float x) {
#if __has_builtin(__builtin_amdgcn_exp2f)
    return __builtin_amdgcn_exp2f(x);
#else
    return exp2f(x);
#endif
}
__device__ __forceinline__ float fast_rcp(float x) {
#if __has_builtin(__builtin_amdgcn_rcpf)
    return __builtin_amdgcn_rcpf(x);
#else
    return __fdividef(1.f, x);
#endif
}

// ---------------- phase 1a: pack W_ih to scaled f16 pairs ----------------
__global__ void pack_wih_kernel(const float* __restrict__ W_ih, int* __restrict__ wpk) {
    int q = blockIdx.x * blockDim.x + threadIdx.x;
    if (q >= WPAIRS) return;
    int row = q >> 4, p = q & 15;
    const float s = (row < 62) ? LOG2E : 2.f * LOG2E;
    float lo = W_ih[row * HH + 2 * p] * s;
    float hi = (2 * p + 1 < HH) ? W_ih[row * HH + 2 * p + 1] * s : 0.f;
    hf2 w; w.x = (_Float16)lo; w.y = (_Float16)hi;
    wpk[q] = __builtin_bit_cast(int, w);
}

// ---------------- phase 1b: xg = (x @ W_ih^T + b_ih) * scale ----------------
__global__ __launch_bounds__(128, 2) void xg_gemm_kernel(
    const float* __restrict__ x, const int* __restrict__ wpk,
    const float* __restrict__ b_ih, _Float16* __restrict__ xg)
{
    const int tid = threadIdx.x;
    const int b   = blockIdx.x;
    const int t0  = tid * 4;                     // 4 consecutive timesteps
    const float* xb = x + ((size_t)b * TT + t0) * HH;

    hf2 xp[4][16];
#pragma unroll
    for (int j = 0; j < 4; ++j)
#pragma unroll
        for (int p = 0; p < 16; ++p) {
            float lo = xb[j * HH + 2 * p];
            float hi = (2 * p + 1 < HH) ? xb[j * HH + 2 * p + 1] : 0.f;
            xp[j][p].x = (_Float16)lo; xp[j][p].y = (_Float16)hi;
        }

    _Float16* xgb = xg + (size_t)b * RR * TT + t0;
    for (int row = 0; row < 93; ++row) {
        const float bi = b_ih[row] * ((row < 62) ? LOG2E : 2.f * LOG2E);
        float a0 = bi, a1 = bi, a2 = bi, a3 = bi;
        const int* wr = wpk + row * 16;                   // uniform -> s_load
#pragma unroll
        for (int p = 0; p < 16; ++p) {
            const int w = wr[p];
            a0 = dot2(w, xp[0][p], a0);
            a1 = dot2(w, xp[1][p], a1);
            a2 = dot2(w, xp[2][p], a2);
            a3 = dot2(w, xp[3][p], a3);
        }
        hf2 lo2; lo2.x = (_Float16)a0; lo2.y = (_Float16)a1;
        hf2 hi2; hi2.x = (_Float16)a2; hi2.y = (_Float16)a3;
        *reinterpret_cast<int2*>(xgb + (size_t)row * TT) =
            make_int2(__builtin_bit_cast(int, lo2), __builtin_bit_cast(int, hi2));
    }
    for (int row = 93; row < 96; ++row)       // zero pad rows
        *reinterpret_cast<int2*>(xgb + (size_t)row * TT) = make_int2(0, 0);
}

// ---------- phase 2: recurrence, 1 batch/wave, MFMA for W_hh.h ----------
__global__ __launch_bounds__(64, 2) void gru_mfma_kernel(
    const _Float16* __restrict__ xg, const float* __restrict__ W_hh,
    const float* __restrict__ b_hh, const float* __restrict__ W_fc,
    const float* __restrict__ b_fc, float* __restrict__ out)
{
    __shared__ float    preF[96];     // y = W.h + b (rows 0..95)
    __shared__ _Float16 hbuf[32];     // h f16, [31] = 0 pad

    const int lane = threadIdx.x & 63;
    const int col  = lane & 15;
    const int grp  = lane >> 4;
    const int b    = blockIdx.x;

    // A fragments: A[c][e] = scaled W row (16c+col), k = grp*8+e.
    hf8 A[6];
#pragma unroll
    for (int c = 0; c < 6; ++c) {
        const int row = 16 * c + col;
#pragma unroll
        for (int e = 0; e < 8; ++e) {
            const int k = grp * 8 + e;
            float v = 0.f;
            if (k < HH) {
                if (row < 62)       v = LOG2E * W_hh[row * HH + k];
                else if (row < 93)  v = 2.f * LOG2E * W_hh[row * HH + k];
                else if (row >= 94) v = W_fc[(row - 94) * HH + k];
            }
            A[c][e] = (_Float16)v;
        }
    }
    // C-in biases: row = 16c + 4*grp + j  [m89 C/D mapping]
    f32x4 CB[6];
#pragma unroll
    for (int c = 0; c < 6; ++c)
#pragma unroll
        for (int j = 0; j < 4; ++j) {
            const int row = 16 * c + 4 * grp + j;
            float v;
            if (row < 62)       v = LOG2E * b_hh[row];
            else if (row < 93)  v = 2.f * LOG2E * b_hh[row];
            else if (row == 93) v = 0.f;
            else                v = b_fc[row - 94];
            CB[c][j] = v;
        }

    // xg streams: gate lane u<31 reads rows u, 31+u, 62+u; others pad row 93.
    int rR = 93, rZ = 93, rN = 93;
    if (lane < HH) { rR = lane; rZ = HH + lane; rN = 2 * HH + lane; }
    const _Float16* gR = xg + ((size_t)b * RR + rR) * TT;
    const _Float16* gZ = xg + ((size_t)b * RR + rZ) * TT;
    const _Float16* gN = xg + ((size_t)b * RR + rN) * TT;
    float* outb = out + (size_t)b * TT * 2;

    if (lane < 32) hbuf[lane] = (_Float16)0.f;    // h_0 = 0 (incl pad)
    MEMFENCE;

    float hold = 0.f;
    int4 bR = *(const int4*)gR;
    int4 bZ = *(const int4*)gZ;
    int4 bN = *(const int4*)gN;

    const char* hb_base = (const char*)&hbuf[0] + (grp << 4);

    for (int tb = 0; tb < TT / 8; ++tb) {
        int4 nR = bR, nZ = bZ, nN = bN;
        if (tb + 1 < TT / 8) {
            nR = *(const int4*)(gR + (size_t)(tb + 1) * 8);
            nZ = *(const int4*)(gZ + (size_t)(tb + 1) * 8);
            nN = *(const int4*)(gN + (size_t)(tb + 1) * 8);
        }
#pragma unroll
        for (int s = 0; s < 8; ++s) {
            const int t = tb * 8 + s;
            // B fragment: h[k], k = grp*8 + e  (16B broadcast read)
            const hf8 Bf = __builtin_bit_cast(hf8, *(const int4*)hb_base);
            const f32x4 D0 = __builtin_amdgcn_mfma_f32_16x16x32_f16(A[0], Bf, CB[0], 0, 0, 0);
            const f32x4 D1 = __builtin_amdgcn_mfma_f32_16x16x32_f16(A[1], Bf, CB[1], 0, 0, 0);
            const f32x4 D2 = __builtin_amdgcn_mfma_f32_16x16x32_f16(A[2], Bf, CB[2], 0, 0, 0);
            const f32x4 D3 = __builtin_amdgcn_mfma_f32_16x16x32_f16(A[3], Bf, CB[3], 0, 0, 0);
            const f32x4 D4 = __builtin_amdgcn_mfma_f32_16x16x32_f16(A[4], Bf, CB[4], 0, 0, 0);
            const f32x4 D5 = __builtin_amdgcn_mfma_f32_16x16x32_f16(A[5], Bf, CB[5], 0, 0, 0);
            MEMFENCE;
            if (col == 0) {                       // rows 16c + 4*grp + j
                *(f32x4*)&preF[ 0 + 4 * grp] = D0;
                *(f32x4*)&preF[16 + 4 * grp] = D1;
                *(f32x4*)&preF[32 + 4 * grp] = D2;
                *(f32x4*)&preF[48 + 4 * grp] = D3;
                *(f32x4*)&preF[64 + 4 * grp] = D4;
                *(f32x4*)&preF[80 + 4 * grp] = D5;
            }
            MEMFENCE;
            if (lane < HH) {
                const float xar = (float)(((const _Float16*)&bR)[s]);
                const float xaz = (float)(((const _Float16*)&bZ)[s]);
                const float xn  = (float)(((const _Float16*)&bN)[s]);
                const float pr  = preF[lane]          + xar;
                const float pz  = preF[HH + lane]     + xaz;
                const float pn  = preF[2 * HH + lane];
                const float r   = fast_rcp(1.f + fast_exp2(-pr));
                const float z   = fast_rcp(1.f + fast_exp2(-pz));
                const float en  = fast_exp2(-fmaf(r, pn, xn));
                const float nn  = fmaf(2.f, fast_rcp(1.f + en), -1.f);
                hold = nn + z * (hold - nn);
                hbuf[lane] = (_Float16)hold;
            } else if (lane == HH && t > 0) {     // FC(h_t) -> out[t-1]
                const float2 fc = *(const float2*)&preF[94];
                *(float2*)(outb + (size_t)(t - 1) * 2) = fc;
            }
            MEMFENCE;
        }
        bR = nR; bZ = nZ; bN = nN;
    }

    // epilogue: FC(h_T) -> out[TT-1]
    {
        const hf8 Bf = __builtin_bit_cast(hf8, *(const int4*)hb_base);
        const f32x4 D5 = __builtin_amdgcn_mfma_f32_16x16x32_f16(A[5], Bf, CB[5], 0, 0, 0);
        MEMFENCE;
        if (col == 0) *(f32x4*)&preF[80 + 4 * grp] = D5;
        MEMFENCE;
        if (lane == HH)
            *(float2*)(outb + (size_t)(TT - 1) * 2) = *(const float2*)&preF[94];
    }
}

// ---------------- fallback (round-3 kernel, used if ws too small) ----------------
__global__ __launch_bounds__(64, 1) void gru_pair_kernel(
    const float* __restrict__ x, const float* __restrict__ W_ih,
    const float* __restrict__ W_hh, const float* __restrict__ b_ih,
    const float* __restrict__ b_hh, const float* __restrict__ W_fc,
    const float* __restrict__ b_fc, float* __restrict__ out)
{
    __shared__ _Float16 hbuf[2][32];
    __shared__ _Float16 xbuf[2][2][32];

    const int lane = threadIdx.x & 63;
    const int li   = lane & 31;
    const int half = lane >> 5;
    const int b    = blockIdx.x * 2 + half;
    const bool unit = (li < HH);

    const float* ph0 = unit ? W_hh + (size_t)li * HH            : W_fc;
    const float* ph1 = unit ? W_hh + (size_t)(HH + li) * HH     : W_fc + HH;
    const float* ph2 = unit ? W_hh + (size_t)(2 * HH + li) * HH : nullptr;
    const float* px0 = unit ? W_ih + (size_t)li * HH            : nullptr;
    const float* px1 = unit ? W_ih + (size_t)(HH + li) * HH     : nullptr;
    const float* px2 = unit ? W_ih + (size_t)(2 * HH + li) * HH : nullptr;

    hf2 wh0[16], wh1[16], wh2[16], wx0[16], wx1[16], wx2[16];
#pragma unroll
    for (int m = 0; m < 16; ++m) {
        auto pk = [&](const float* p) -> hf2 {
            hf2 r;
            r.x = p ? (_Float16)p[2 * m] : (_Float16)0.f;
            r.y = (p && (2 * m + 1) < HH) ? (_Float16)p[2 * m + 1] : (_Float16)0.f;
            return r;
        };
        wh0[m] = pk(ph0); wh1[m] = pk(ph1); wh2[m] = pk(ph2);
        wx0[m] = pk(px0); wx1[m] = pk(px1); wx2[m] = pk(px2);
    }

    float arH0, azH0, anH0, anX0;
    if (unit) {
        arH0 = b_ih[li] + b_hh[li];
        azH0 = b_ih[HH + li] + b_hh[HH + li];
        anH0 = b_hh[2 * HH + li];
        anX0 = b_ih[2 * HH + li];
    } else {
        arH0 = b_fc[0]; azH0 = b_fc[1]; anH0 = 0.f; anX0 = 0.f;
    }

    const float* xb   = x + (size_t)b * TT * HH;
    float*       outb = out + (size_t)b * TT * 2;

    hbuf[half][li]    = (_Float16)0.f;
    xbuf[0][half][li] = unit ? (_Float16)xb[li]      : (_Float16)0.f;
    xbuf[1][half][li] = unit ? (_Float16)xb[HH + li] : (_Float16)0.f;
    MEMFENCE;
    float xpre = unit ? xb[(size_t)2 * HH + li] : 0.f;
    float hval = 0.f;

    const int4* HP  = (const int4*)(&hbuf[half][0]);
    const int4* XB0 = (const int4*)(&xbuf[0][half][0]);
    const int4* XB1 = (const int4*)(&xbuf[1][half][0]);

    int4 xq0 = XB0[0], xq1 = XB0[1], xq2 = XB0[2], xq3 = XB0[3];

#pragma unroll 2
    for (int t = 0; t < TT; ++t) {
        int4 hq0 = HP[0], hq1 = HP[1], hq2 = HP[2], hq3 = HP[3];

        float arH = arH0, azH = azH0, anH = anH0;
        float arX = 0.f, azX = 0.f, anX = anX0;
#define STEPM(m, hp, xp) \
        arH = dot2(hp, wh0[m], arH); azH = dot2(hp, wh1[m], azH); \
        anH = dot2(hp, wh2[m], anH); arX = dot2(xp, wx0[m], arX); \
        azX = dot2(xp, wx1[m], azX); anX = dot2(xp, wx2[m], anX);
        STEPM(0,  hq0.x, xq0.x) STEPM(1,  hq0.y, xq0.y)
        STEPM(2,  hq0.z, xq0.z) STEPM(3,  hq0.w, xq0.w)
        STEPM(4,  hq1.x, xq1.x) STEPM(5,  hq1.y, xq1.y)
        STEPM(6,  hq1.z, xq1.z) STEPM(7,  hq1.w, xq1.w)
        STEPM(8,  hq2.x, xq2.x) STEPM(9,  hq2.y, xq2.y)
        STEPM(10, hq2.z, xq2.z) STEPM(11, hq2.w, xq2.w)
        STEPM(12, hq3.x, xq3.x) STEPM(13, hq3.y, xq3.y)
        STEPM(14, hq3.z, xq3.z) STEPM(15, hq3.w, xq3.w)
#undef STEPM

        const float sumr = arH + arX;
        const float sumz = azH + azX;
        if (lane == 31 && t > 0)
            *(float2*)(outb + (size_t)(t - 1) * 2) = make_float2(sumr, sumz);

        const float r    = __fdividef(1.f, 1.f + __expf(-sumr));
        const float z    = __fdividef(1.f, 1.f + __expf(-sumz));
        const float npre = fmaf(r, anH, anX);
        const float nn   = __fdividef(2.f, 1.f + __expf(-2.f * npre)) - 1.f;
        const float hnew = nn + z * (hval - nn);
        hval = unit ? hnew : 0.f;
        hbuf[half][li] = (_Float16)hval;

        xbuf[t & 1][half][li] = unit ? (_Float16)xpre : (_Float16)0.f;
        MEMFENCE;
        int tn = t + 3; if (tn > TT - 1) tn = TT - 1;
        xpre = unit ? xb[(size_t)tn * HH + li] : 0.f;

        const int4* XN = (t & 1) ? XB0 : XB1;
        xq0 = XN[0]; xq1 = XN[1]; xq2 = XN[2]; xq3 = XN[3];
    }

    {
        int4 hq0 = HP[0], hq1 = HP[1], hq2 = HP[2], hq3 = HP[3];
        float f0 = arH0, f1 = azH0;
#define FST(m, hp) f0 = dot2(hp, wh0[m], f0); f1 = dot2(hp, wh1[m], f1);
        FST(0,  hq0.x) FST(1,  hq0.y) FST(2,  hq0.z) FST(3,  hq0.w)
        FST(4,  hq1.x) FST(5,  hq1.y) FST(6,  hq1.z) FST(7,  hq1.w)
        FST(8,  hq2.x) FST(9,  hq2.y) FST(10, hq2.z) FST(11, hq2.w)
        FST(12, hq3.x) FST(13, hq3.y) FST(14, hq3.z) FST(15, hq3.w)
#undef FST
        if (lane == 31)
            *(float2*)(outb + (size_t)(TT - 1) * 2) = make_float2(f0, f1);
    }
}

extern "C" void kernel_launch(void* const* d_in, const int* in_sizes, int n_in,
                              void* d_out, int out_size, void* d_ws, size_t ws_size,
                              hipStream_t stream) {
    const float* x    = (const float*)d_in[0];
    const float* W_ih = (const float*)d_in[1];
    const float* W_hh = (const float*)d_in[2];
    const float* b_ih = (const float*)d_in[3];
    const float* b_hh = (const float*)d_in[4];
    const float* W_fc = (const float*)d_in[5];
    const float* b_fc = (const float*)d_in[6];
    float* out = (float*)d_out;

    if (ws_size >= WS_NEEDED) {
        _Float16* xg = (_Float16*)d_ws;
        int* wpk = (int*)((char*)d_ws + XG_BYTES);
        pack_wih_kernel<<<(WPAIRS + 255) / 256, 256, 0, stream>>>(W_ih, wpk);
        xg_gemm_kernel<<<BB, 128, 0, stream>>>(x, wpk, b_ih, xg);
        gru_mfma_kernel<<<BB, 64, 0, stream>>>(xg, W_hh, b_hh, W_fc, b_fc, out);
    } else {
        gru_pair_kernel<<<BB / 2, 64, 0, stream>>>(x, W_ih, W_hh, b_ih, b_hh,
                                                   W_fc, b_fc, out);
    }
}

// Round 10
// 325.217 us; speedup vs baseline: 1.2430x; 1.2430x over previous
//
#include <hip/hip_runtime.h>

// GRU H=31, B=2048, T=512, FC->2 — SINGLE KERNEL, all-register recurrence.
//
// One wave64 = 16 batches (col = lane&15), 128 waves total.
// Per step t: D_x = A_x·B_x + C_x (6 MFMA, B_x = x_t f16, bias b_ih in C),
//             D_h = A_h·B_h + C_h (6 MFMA, B_h = h_t f16, bias b_hh in C).
// Row permutation pi: unit u = 8*grp+s, gate m (0=r,1=z,2=n) -> position
//   q = 3s+m, c = q>>2, j = q&3, p = 16c + 4*grp + j
// so lane (col,grp) holds ALL gate preacts of its 8 units at literal (c,j)
// register indices (D-layout: col=lane&15, row=16c+4*grp+j, r9-verified),
// computes gates in-lane, and repacks h into its own B_h k-segment
// (k = 8*grp+e == units 8*grp..8*grp+7). Zero LDS, zero cross-lane, zero
// barriers. FC head at positions 94/95 (grp3, c=5, j=2/3), b_fc in C_h.
// r/z rows pre-scaled by log2e, n rows by 2log2e (exp2-native gates),
// FC rows unscaled.
// x-side k split: grp0/1: k=0..15; grp2: k=16..23 (weight for k=23 zeroed);
// grp3 loads x[23..30] (avoids OOB at array end) with A_x cols shifted.
// x prefetched 2 steps ahead (double buffer) to cover HBM latency.

constexpr int BB = 2048, TT = 512, HH = 31;
constexpr float LOG2E = 1.4426950408889634f;

typedef _Float16 hf8 __attribute__((ext_vector_type(8)));
typedef float f32x4 __attribute__((ext_vector_type(4)));

__device__ __forceinline__ float fast_exp2(float v) {
#if __has_builtin(__builtin_amdgcn_exp2f)
    return __builtin_amdgcn_exp2f(v);
#else
    return exp2f(v);
#endif
}
__device__ __forceinline__ float fast_rcp(float v) {
#if __has_builtin(__builtin_amdgcn_rcpf)
    return __builtin_amdgcn_rcpf(v);
#else
    return __fdividef(1.f, v);
#endif
}
__device__ __forceinline__ unsigned pk2(float a, float b) {
    return __builtin_bit_cast(unsigned, __builtin_amdgcn_cvt_pkrtz(a, b));
}

struct F8 { float v0, v1, v2, v3, v4, v5, v6, v7; };
__device__ __forceinline__ void ldx(F8* d, const float* p) {
    __builtin_memcpy(d, p, 32);          // align-4 source; compiler picks legal loads
}

__global__ __launch_bounds__(64, 1) void gru_one_kernel(
    const float* __restrict__ x, const float* __restrict__ W_ih,
    const float* __restrict__ W_hh, const float* __restrict__ b_ih,
    const float* __restrict__ b_hh, const float* __restrict__ W_fc,
    const float* __restrict__ b_fc, float* __restrict__ out)
{
    const int lane  = threadIdx.x & 63;
    const int col   = lane & 15;
    const int grp   = lane >> 4;
    const int batch = blockIdx.x * 16 + col;

    // ---------- A fragments: A-row (in tile) = lane&15, k = grp*8+e ----------
    hf8 Ah[6], Ax[6];
    {
        const int gp = col >> 2, jj = col & 3;       // row-position owner grp / j
#pragma unroll
        for (int c = 0; c < 6; ++c) {
            const int q = 4 * c + jj, s = q / 3, m = q - 3 * s, u = 8 * gp + s;
#pragma unroll
            for (int e = 0; e < 8; ++e) {
                const int kh = 8 * grp + e;                    // h-side k
                const int kx = kh - (grp == 3 ? 1 : 0);        // x-side logical k
                float vh = 0.f, vx = 0.f;
                if (u == 31) {                                  // FC / pad rows
                    if (q == 22 && kh < HH) vh = W_fc[kh];
                    if (q == 23 && kh < HH) vh = W_fc[HH + kh];
                } else {
                    const float sc = (m == 2) ? 2.f * LOG2E : LOG2E;
                    const int row = 31 * m + u;
                    if (kh < HH) vh = sc * W_hh[row * HH + kh];
                    if (!(grp == 2 && e == 7)) vx = sc * W_ih[row * HH + kx];
                }
                Ah[c][e] = (_Float16)vh;
                Ax[c][e] = (_Float16)vx;
            }
        }
    }

    // ---------- C bias fragments: D-row = 16c + 4*grp + j ----------
    f32x4 Ch[6], Cx[6];
#pragma unroll
    for (int c = 0; c < 6; ++c)
#pragma unroll
        for (int j = 0; j < 4; ++j) {
            const int q = 4 * c + j, s = q / 3, m = q - 3 * s, u = 8 * grp + s;
            float vh = 0.f, vx = 0.f;
            if (u == 31) {
                if (q == 22) vh = b_fc[0];
                if (q == 23) vh = b_fc[1];
            } else {
                const float sc = (m == 2) ? 2.f * LOG2E : LOG2E;
                vh = sc * b_hh[31 * m + u];
                vx = sc * b_ih[31 * m + u];
            }
            Ch[c][j] = vh;
            Cx[c][j] = vx;
        }

    const float* xb  = x + (size_t)batch * TT * HH + (8 * grp - (grp == 3 ? 1 : 0));
    float*      outp = out + (size_t)batch * TT * 2;

    float h0 = 0.f, h1 = 0.f, h2 = 0.f, h3 = 0.f,
          h4 = 0.f, h5 = 0.f, h6 = 0.f, h7 = 0.f;
    int4 bhi = make_int4(0, 0, 0, 0);               // packed f16 h (B_h frag)

    F8 xA, xB;
    ldx(&xA, xb);                                   // x_0
    ldx(&xB, xb + HH);                              // x_1

#define GATE(ca,ja, cb,jb, cc,jc, H) { \
        const float pr  = Dh[ca][ja] + Dx[ca][ja]; \
        const float pz  = Dh[cb][jb] + Dx[cb][jb]; \
        const float pnh = Dh[cc][jc]; \
        const float xn  = Dx[cc][jc]; \
        const float r   = fast_rcp(1.f + fast_exp2(-pr)); \
        const float z   = fast_rcp(1.f + fast_exp2(-pz)); \
        const float en  = fast_exp2(-fmaf(r, pnh, xn)); \
        const float nn  = fmaf(2.f, fast_rcp(1.f + en), -1.f); \
        H = nn + z * (H - nn); \
    }

#define STEP_BODY(T, XS) { \
        const int4 bxi = make_int4(pk2(XS.v0, XS.v1), pk2(XS.v2, XS.v3), \
                                   pk2(XS.v4, XS.v5), pk2(XS.v6, XS.v7)); \
        const hf8 Bx = __builtin_bit_cast(hf8, bxi); \
        const hf8 Bh = __builtin_bit_cast(hf8, bhi); \
        f32x4 Dh[6], Dx[6]; \
        Dx[0] = __builtin_amdgcn_mfma_f32_16x16x32_f16(Ax[0], Bx, Cx[0], 0, 0, 0); \
        Dx[1] = __builtin_amdgcn_mfma_f32_16x16x32_f16(Ax[1], Bx, Cx[1], 0, 0, 0); \
        Dx[2] = __builtin_amdgcn_mfma_f32_16x16x32_f16(Ax[2], Bx, Cx[2], 0, 0, 0); \
        Dx[3] = __builtin_amdgcn_mfma_f32_16x16x32_f16(Ax[3], Bx, Cx[3], 0, 0, 0); \
        Dx[4] = __builtin_amdgcn_mfma_f32_16x16x32_f16(Ax[4], Bx, Cx[4], 0, 0, 0); \
        Dx[5] = __builtin_amdgcn_mfma_f32_16x16x32_f16(Ax[5], Bx, Cx[5], 0, 0, 0); \
        Dh[0] = __builtin_amdgcn_mfma_f32_16x16x32_f16(Ah[0], Bh, Ch[0], 0, 0, 0); \
        Dh[1] = __builtin_amdgcn_mfma_f32_16x16x32_f16(Ah[1], Bh, Ch[1], 0, 0, 0); \
        Dh[2] = __builtin_amdgcn_mfma_f32_16x16x32_f16(Ah[2], Bh, Ch[2], 0, 0, 0); \
        Dh[3] = __builtin_amdgcn_mfma_f32_16x16x32_f16(Ah[3], Bh, Ch[3], 0, 0, 0); \
        Dh[4] = __builtin_amdgcn_mfma_f32_16x16x32_f16(Ah[4], Bh, Ch[4], 0, 0, 0); \
        Dh[5] = __builtin_amdgcn_mfma_f32_16x16x32_f16(Ah[5], Bh, Ch[5], 0, 0, 0); \
        if (grp == 3 && (T) > 0) \
            *(float2*)(outp + (size_t)((T) - 1) * 2) = make_float2(Dh[5][2], Dh[5][3]); \
        GATE(0,0, 0,1, 0,2, h0)  GATE(0,3, 1,0, 1,1, h1) \
        GATE(1,2, 1,3, 2,0, h2)  GATE(2,1, 2,2, 2,3, h3) \
        GATE(3,0, 3,1, 3,2, h4)  GATE(3,3, 4,0, 4,1, h5) \
        GATE(4,2, 4,3, 5,0, h6)  GATE(5,1, 5,2, 5,3, h7) \
        if (grp == 3) h7 = 0.f;                      /* unit-31 pad */ \
        bhi = make_int4(pk2(h0, h1), pk2(h2, h3), pk2(h4, h5), pk2(h6, h7)); \
    }

    for (int t = 0; t < TT; t += 2) {
        // even step: consume xA, prefetch x_{t+2} into xA
        {
            const F8 xs = xA;
            if (t + 2 < TT) ldx(&xA, xb + (size_t)(t + 2) * HH);
            STEP_BODY(t, xs)
        }
        // odd step: consume xB, prefetch x_{t+3} into xB
        {
            const F8 xs = xB;
            if (t + 3 < TT) ldx(&xB, xb + (size_t)(t + 3) * HH);
            STEP_BODY(t + 1, xs)
        }
    }

    // epilogue: FC(h_T) -> out[TT-1]
    {
        const hf8 Bh = __builtin_bit_cast(hf8, bhi);
        const f32x4 D5 = __builtin_amdgcn_mfma_f32_16x16x32_f16(Ah[5], Bh, Ch[5], 0, 0, 0);
        if (grp == 3)
            *(float2*)(outp + (size_t)(TT - 1) * 2) = make_float2(D5[2], D5[3]);
    }
#undef STEP_BODY
#undef GATE
}

extern "C" void kernel_launch(void* const* d_in, const int* in_sizes, int n_in,
                              void* d_out, int out_size, void* d_ws, size_t ws_size,
                              hipStream_t stream) {
    const float* x    = (const float*)d_in[0];
    const float* W_ih = (const float*)d_in[1];
    const float* W_hh = (const float*)d_in[2];
    const float* b_ih = (const float*)d_in[3];
    const float* b_hh = (const float*)d_in[4];
    const float* W_fc = (const float*)d_in[5];
    const float* b_fc = (const float*)d_in[6];
    float* out = (float*)d_out;

    gru_one_kernel<<<BB / 16, 64, 0, stream>>>(x, W_ih, W_hh, b_ih, b_hh,
                                               W_fc, b_fc, out);
}

// Round 11
// 296.787 us; speedup vs baseline: 1.3621x; 1.0958x over previous
//
#include <hip/hip_runtime.h>

// GRU H=31, B=2048, T=512, FC->2 — SINGLE KERNEL, all-register recurrence.
//
// One wave64 = 16 batches (col = lane&15), 128 waves total.
// Row layout (NEW in r11): tiles 0,1 = r-rows, tiles 2,3 = z-rows,
// tiles 4,5 = n-rows. Position p = 16c + 4*grp + j holds gate-row of unit
// u = 8*grp + 4*(c&1... c mod 2 block) + j  (u = 8*grp + 4*(c-base) + j).
// FC0 lives in the unit-31 pad slot p=31 (c=1,grp=3,j=3), FC1 at p=63.
//
// Per step: Dx[c] = Ax[c]·Bx + Cx[c]   (6 MFMA, x-side, biases in C)
//           Dh[c] = Ah[c]·Bh + Dx[c]   (c=0..3: r/z preacts DIRECTLY)
//           Dh[c] = Ah[c]·Bh + Chn     (c=4,5: n h-part, x-part kept in Dx)
// Gates stage-parallel (8-way ILP per stage), rcp-combined sigmoids:
//   R = rcp((1+er)(1+ez)); r = (1+ez)R; z = (1+er)R  (5 trans/unit).
// Lane repacks its own h (k-segment == its units). Zero LDS / cross-lane /
// barriers. r/z rows pre-scaled log2e, n rows 2log2e (exp2-native gates).
// D-layout col=lane&15, row=16c+4grp+j and B-col=batch: HW-verified r9/r10.
// x-side k split: grp0/1 k=0..15; grp2 k=16..23 (k=23 weight zeroed);
// grp3 loads x[23..30] (A cols shifted) to avoid OOB. x double-buffered.

constexpr int BB = 2048, TT = 512, HH = 31;
constexpr float LOG2E = 1.4426950408889634f;

typedef _Float16 hf8 __attribute__((ext_vector_type(8)));
typedef float f32x4 __attribute__((ext_vector_type(4)));

__device__ __forceinline__ float fast_exp2(float v) {
#if __has_builtin(__builtin_amdgcn_exp2f)
    return __builtin_amdgcn_exp2f(v);
#else
    return exp2f(v);
#endif
}
__device__ __forceinline__ float fast_rcp(float v) {
#if __has_builtin(__builtin_amdgcn_rcpf)
    return __builtin_amdgcn_rcpf(v);
#else
    return __fdividef(1.f, v);
#endif
}
__device__ __forceinline__ unsigned pk2(float a, float b) {
    return __builtin_bit_cast(unsigned, __builtin_amdgcn_cvt_pkrtz(a, b));
}

struct F8 { float v0, v1, v2, v3, v4, v5, v6, v7; };
__device__ __forceinline__ void ldx(F8* d, const float* p) {
    __builtin_memcpy(d, p, 32);
}

__global__ __launch_bounds__(64, 1) void gru_one_kernel(
    const float* __restrict__ x, const float* __restrict__ W_ih,
    const float* __restrict__ W_hh, const float* __restrict__ b_ih,
    const float* __restrict__ b_hh, const float* __restrict__ W_fc,
    const float* __restrict__ b_fc, float* __restrict__ out)
{
    const int lane  = threadIdx.x & 63;
    const int col   = lane & 15;
    const int grp   = lane >> 4;
    const int batch = blockIdx.x * 16 + col;

    // ---------- A fragments: row-in-tile = lane&15 = (owner<<2)|j ----------
    hf8 Ah[6], Ax[6];
    {
        const int gp = col >> 2, jj = col & 3;   // D-owner grp / j of this row
#pragma unroll
        for (int c = 0; c < 6; ++c) {
            const int base = (c >> 1);                     // 0=r,1=z,2=n
            const int u    = 8 * gp + 4 * (c & 1) + jj;    // unit
            const bool fc0 = (base == 0 && u == 31);
            const bool fc1 = (base == 1 && u == 31);
            const bool pad = (base == 2 && u == 31);
            const float sc = (base == 2) ? 2.f * LOG2E : LOG2E;
            const int wrow = 31 * base + u;                // W row (if !fc/!pad)
#pragma unroll
            for (int e = 0; e < 8; ++e) {
                const int kh = 8 * grp + e;
                const int kx = kh - (grp == 3 ? 1 : 0);
                float vh = 0.f, vx = 0.f;
                if (fc0)      { if (kh < HH) vh = W_fc[kh]; }
                else if (fc1) { if (kh < HH) vh = W_fc[HH + kh]; }
                else if (!pad) {
                    if (kh < HH) vh = sc * W_hh[wrow * HH + kh];
                    if (!(grp == 2 && e == 7)) vx = sc * W_ih[wrow * HH + kx];
                }
                Ah[c][e] = (_Float16)vh;
                Ax[c][e] = (_Float16)vx;
            }
        }
    }

    // ---------- C fragments at D position p = 16c + 4*grp + j ----------
    f32x4 Cx[6], Chn[2];
#pragma unroll
    for (int c = 0; c < 6; ++c)
#pragma unroll
        for (int j = 0; j < 4; ++j) {
            const int base = (c >> 1);
            const int u    = 8 * grp + 4 * (c & 1) + j;
            float vx = 0.f;
            if (u == 31) {
                if (base == 0) vx = b_fc[0];
                else if (base == 1) vx = b_fc[1];
            } else if (base < 2) {
                vx = LOG2E * (b_ih[31 * base + u] + b_hh[31 * base + u]);
            } else {
                vx = 2.f * LOG2E * b_ih[62 + u];
            }
            Cx[c][j] = vx;
            if (base == 2) Chn[c - 4][j] = (u == 31) ? 0.f : 2.f * LOG2E * b_hh[62 + u];
        }

    const float* xb  = x + (size_t)batch * TT * HH + (8 * grp - (grp == 3 ? 1 : 0));
    float*      outp = out + (size_t)batch * TT * 2;

    float hreg[8];
#pragma unroll
    for (int s = 0; s < 8; ++s) hreg[s] = 0.f;
    int4 bhi = make_int4(0, 0, 0, 0);

    F8 xA, xB;
    ldx(&xA, xb);
    ldx(&xB, xb + HH);

#define STEP_BODY(T, XS) { \
        const int4 bxi = make_int4(pk2(XS.v0, XS.v1), pk2(XS.v2, XS.v3), \
                                   pk2(XS.v4, XS.v5), pk2(XS.v6, XS.v7)); \
        const hf8 Bx = __builtin_bit_cast(hf8, bxi); \
        const hf8 Bh = __builtin_bit_cast(hf8, bhi); \
        f32x4 Dx[6], Dh[6]; \
        Dx[0] = __builtin_amdgcn_mfma_f32_16x16x32_f16(Ax[0], Bx, Cx[0], 0, 0, 0); \
        Dx[1] = __builtin_amdgcn_mfma_f32_16x16x32_f16(Ax[1], Bx, Cx[1], 0, 0, 0); \
        Dx[2] = __builtin_amdgcn_mfma_f32_16x16x32_f16(Ax[2], Bx, Cx[2], 0, 0, 0); \
        Dx[3] = __builtin_amdgcn_mfma_f32_16x16x32_f16(Ax[3], Bx, Cx[3], 0, 0, 0); \
        Dx[4] = __builtin_amdgcn_mfma_f32_16x16x32_f16(Ax[4], Bx, Cx[4], 0, 0, 0); \
        Dx[5] = __builtin_amdgcn_mfma_f32_16x16x32_f16(Ax[5], Bx, Cx[5], 0, 0, 0); \
        Dh[0] = __builtin_amdgcn_mfma_f32_16x16x32_f16(Ah[0], Bh, Dx[0], 0, 0, 0); \
        Dh[1] = __builtin_amdgcn_mfma_f32_16x16x32_f16(Ah[1], Bh, Dx[1], 0, 0, 0); \
        Dh[2] = __builtin_amdgcn_mfma_f32_16x16x32_f16(Ah[2], Bh, Dx[2], 0, 0, 0); \
        Dh[3] = __builtin_amdgcn_mfma_f32_16x16x32_f16(Ah[3], Bh, Dx[3], 0, 0, 0); \
        Dh[4] = __builtin_amdgcn_mfma_f32_16x16x32_f16(Ah[4], Bh, Chn[0], 0, 0, 0); \
        Dh[5] = __builtin_amdgcn_mfma_f32_16x16x32_f16(Ah[5], Bh, Chn[1], 0, 0, 0); \
        if (grp == 3 && (T) > 0) \
            *(float2*)(outp + (size_t)((T) - 1) * 2) = make_float2(Dh[1][3], Dh[3][3]); \
        float er[8], ez[8], aa[8], bb[8], RR[8], rr[8], zz[8], en[8], nv[8]; \
        _Pragma("unroll") \
        for (int s = 0; s < 8; ++s) { \
            er[s] = fast_exp2(-Dh[s >> 2][s & 3]); \
            ez[s] = fast_exp2(-Dh[2 + (s >> 2)][s & 3]); \
        } \
        _Pragma("unroll") \
        for (int s = 0; s < 8; ++s) { aa[s] = 1.f + er[s]; bb[s] = 1.f + ez[s]; } \
        _Pragma("unroll") \
        for (int s = 0; s < 8; ++s) RR[s] = fast_rcp(aa[s] * bb[s]); \
        _Pragma("unroll") \
        for (int s = 0; s < 8; ++s) { rr[s] = bb[s] * RR[s]; zz[s] = aa[s] * RR[s]; } \
        _Pragma("unroll") \
        for (int s = 0; s < 8; ++s) \
            en[s] = fast_exp2(-fmaf(rr[s], Dh[4 + (s >> 2)][s & 3], Dx[4 + (s >> 2)][s & 3])); \
        _Pragma("unroll") \
        for (int s = 0; s < 8; ++s) nv[s] = fmaf(2.f, fast_rcp(1.f + en[s]), -1.f); \
        _Pragma("unroll") \
        for (int s = 0; s < 8; ++s) hreg[s] = fmaf(zz[s], hreg[s] - nv[s], nv[s]); \
        if (grp == 3) hreg[7] = 0.f;                 /* unit-31 pad */ \
        bhi = make_int4(pk2(hreg[0], hreg[1]), pk2(hreg[2], hreg[3]), \
                        pk2(hreg[4], hreg[5]), pk2(hreg[6], hreg[7])); \
    }

    for (int t = 0; t < TT; t += 2) {
        {
            const F8 xs = xA;
            if (t + 2 < TT) ldx(&xA, xb + (size_t)(t + 2) * HH);
            STEP_BODY(t, xs)
        }
        {
            const F8 xs = xB;
            if (t + 3 < TT) ldx(&xB, xb + (size_t)(t + 3) * HH);
            STEP_BODY(t + 1, xs)
        }
    }

    // epilogue: FC(h_T) -> out[TT-1]  (FC slots p31/p63; Ax rows there are 0,
    // so C = Cx[1]/Cx[3] reproduces b_fc at the FC positions)
    {
        const hf8 Bh = __builtin_bit_cast(hf8, bhi);
        const f32x4 D1 = __builtin_amdgcn_mfma_f32_16x16x32_f16(Ah[1], Bh, Cx[1], 0, 0, 0);
        const f32x4 D3 = __builtin_amdgcn_mfma_f32_16x16x32_f16(Ah[3], Bh, Cx[3], 0, 0, 0);
        if (grp == 3)
            *(float2*)(outp + (size_t)(TT - 1) * 2) = make_float2(D1[3], D3[3]);
    }
#undef STEP_BODY
}

extern "C" void kernel_launch(void* const* d_in, const int* in_sizes, int n_in,
                              void* d_out, int out_size, void* d_ws, size_t ws_size,
                              hipStream_t stream) {
    const float* x    = (const float*)d_in[0];
    const float* W_ih = (const float*)d_in[1];
    const float* W_hh = (const float*)d_in[2];
    const float* b_ih = (const float*)d_in[3];
    const float* b_hh = (const float*)d_in[4];
    const float* W_fc = (const float*)d_in[5];
    const float* b_fc = (const float*)d_in[6];
    float* out = (float*)d_out;

    gru_one_kernel<<<BB / 16, 64, 0, stream>>>(x, W_ih, W_hh, b_ih, b_hh,
                                               W_fc, b_fc, out);
}